// Round 2
// baseline (244.425 us; speedup 1.0000x reference)
//
#include <hip/hip_runtime.h>

// WeightedKappaLoss: kappa = 1 - (N * sum(W*conf)) / sum(W_ij * ht_i * hp_j)
// conf = 6x6 confusion histogram of (y_true, argmax(y_pred_row)).
// softmax is monotone -> argmax on raw logits. All counts exact integers;
// final ratio in double (absmax == 0 vs reference in prior rounds).
//
// R2 (resubmit of R1 after container-level infra failure; kernel audited:
// no spin-waits, no divergent barriers, memset-in-capture is used by the
// harness itself): single fused kernel. Per-wave LDS sub-histograms (no
// inter-wave atomic serialization), 2048 blocks (8/CU -> 32 waves/CU for
// load latency hiding), per-block merge into 8 replicated global bin sets
// (atomic contention 2048/8=256 per address, overlapped with block-finish
// skew), last block (device atomic counter) computes kappa in-kernel. The
// 576-thread stage-2 kernel is replaced by a 1.2 KB memset graph node.

#define NC 6
#define NBINS 36
#define NREP 8           // global bin replicas: cuts same-address serialization 8x
#define GRID 2048        // 8 blocks/CU on 256 CUs -> full 32-wave occupancy
#define BLOCK 256

__global__ __launch_bounds__(BLOCK) void kappa_fused(
    const float4* __restrict__ yp4, const int2* __restrict__ yt2,
    const float* __restrict__ yp, const int* __restrict__ yt,
    unsigned int* __restrict__ gbins,    // [NREP][NBINS], zeroed per launch
    unsigned int* __restrict__ counter,  // zeroed per launch
    float* __restrict__ out, int npairs, int N) {
    __shared__ unsigned int sconf[4][NBINS];  // one 36-bin histogram per wave
    __shared__ unsigned int stot[NBINS];
    __shared__ unsigned int last_flag;
    const int tid = threadIdx.x;
    if (tid < 4 * NBINS) ((unsigned int*)sconf)[tid] = 0u;
    if (tid == 0) last_flag = 0u;
    __syncthreads();

    unsigned int* __restrict__ my = sconf[tid >> 6];
    const int stride = gridDim.x * blockDim.x;
    for (int i = blockIdx.x * blockDim.x + tid; i < npairs; i += stride) {
        const float4 a = yp4[3 * i];
        const float4 b = yp4[3 * i + 1];
        const float4 c = yp4[3 * i + 2];
        const int2 t = yt2[i];

        // row 0: a.x a.y a.z a.w b.x b.y  (strict > keeps first max = jnp.argmax)
        float m = a.x; int p = 0;
        if (a.y > m) { m = a.y; p = 1; }
        if (a.z > m) { m = a.z; p = 2; }
        if (a.w > m) { m = a.w; p = 3; }
        if (b.x > m) { m = b.x; p = 4; }
        if (b.y > m) { m = b.y; p = 5; }
        atomicAdd(&my[t.x * NC + p], 1u);

        // row 1: b.z b.w c.x c.y c.z c.w
        m = b.z; p = 0;
        if (b.w > m) { m = b.w; p = 1; }
        if (c.x > m) { m = c.x; p = 2; }
        if (c.y > m) { m = c.y; p = 3; }
        if (c.z > m) { m = c.z; p = 4; }
        if (c.w > m) { m = c.w; p = 5; }
        atomicAdd(&my[t.y * NC + p], 1u);
    }

    // odd-N tail (N=4e6 is even; kept for generality)
    if ((N & 1) && blockIdx.x == 0 && tid == 0) {
        const int r = N - 1;
        float m = yp[r * NC]; int p = 0;
        #pragma unroll
        for (int j = 1; j < NC; ++j) {
            const float v = yp[r * NC + j];
            if (v > m) { m = v; p = j; }
        }
        atomicAdd(&my[yt[r] * NC + p], 1u);
    }
    __syncthreads();

    // Per-block merge of the 4 wave histograms -> one replicated global set.
    // Device-scope atomicAdd (default on CDNA) -> cross-XCD safe.
    if (tid < NBINS) {
        const unsigned int s =
            sconf[0][tid] + sconf[1][tid] + sconf[2][tid] + sconf[3][tid];
        if (s) atomicAdd(&gbins[(blockIdx.x & (NREP - 1)) * NBINS + tid], s);
    }
    __syncthreads();

    // Last-block-done detection (canonical threadfence reduction pattern).
    // No spin anywhere: non-last blocks just exit.
    if (tid == 0) {
        __threadfence();  // bins globally visible before counter bump
        if (atomicAdd(counter, 1u) == (unsigned int)(GRID - 1)) last_flag = 1u;
    }
    __syncthreads();
    if (!last_flag) return;

    // Finalize in the last block. Agent-scope atomic loads hit the coherence
    // point (bypass potentially-stale L1/local-L2 lines across XCDs).
    if (tid < NBINS) {
        unsigned int s = 0;
        #pragma unroll
        for (int r = 0; r < NREP; ++r)
            s += __hip_atomic_load(&gbins[r * NBINS + tid], __ATOMIC_RELAXED,
                                   __HIP_MEMORY_SCOPE_AGENT);
        stot[tid] = s;   // per-bin total <= N=4e6, exact in u32
    }
    __syncthreads();
    if (tid == 0) {
        long long conf[NBINS], ht[NC], hp[NC];
        #pragma unroll
        for (int i = 0; i < NC; ++i) { ht[i] = 0; hp[i] = 0; }
        #pragma unroll
        for (int k = 0; k < NBINS; ++k) conf[k] = (long long)stot[k];

        long long num = 0;
        #pragma unroll
        for (int i = 0; i < NC; ++i)
            #pragma unroll
            for (int j = 0; j < NC; ++j) {
                const long long w = (long long)(i - j) * (i - j);
                num += w * conf[i * NC + j];
                ht[i] += conf[i * NC + j];
                hp[j] += conf[i * NC + j];
            }
        long long den = 0;
        #pragma unroll
        for (int i = 0; i < NC; ++i)
            #pragma unroll
            for (int j = 0; j < NC; ++j)
                den += (long long)(i - j) * (i - j) * ht[i] * hp[j];

        out[0] = (float)(1.0 - ((double)num * (double)(long long)N) / (double)den);
    }
}

extern "C" void kernel_launch(void* const* d_in, const int* in_sizes, int n_in,
                              void* d_out, int out_size, void* d_ws, size_t ws_size,
                              hipStream_t stream) {
    const float* yp = (const float*)d_in[0];
    const int* yt = (const int*)d_in[1];   // int32 on device (verified: absmax=0)
    const int N = in_sizes[1];
    unsigned int* gbins = (unsigned int*)d_ws;           // NREP*NBINS uints
    unsigned int* counter = gbins + NREP * NBINS;        // +1 uint

    // Zero the replicated bins + done-counter (graph-capturable memset node —
    // the harness's own reset() uses hipMemsetAsync; required every launch
    // since the harness poisons the workspace between iters).
    hipMemsetAsync(d_ws, 0, (NREP * NBINS + 1) * sizeof(unsigned int), stream);

    const int npairs = N / 2;
    kappa_fused<<<GRID, BLOCK, 0, stream>>>(
        (const float4*)yp, (const int2*)yt, yp, yt, gbins, counter,
        (float*)d_out, npairs, N);
}

// Round 4
// 155.641 us; speedup vs baseline: 1.5704x; 1.5704x over previous
//
#include <hip/hip_runtime.h>

// WeightedKappaLoss: kappa = 1 - (N * sum(W*conf)) / sum(W_ij * ht_i * hp_j)
// conf = 6x6 confusion histogram of (y_true, argmax(y_pred_row)).
// softmax is monotone -> argmax on raw logits. All counts exact integers;
// final ratio in double -> absmax == 0 vs reference (verified R0/R2).
//
// R4: R3's LDS bounce raced because LLVM's PER-LANE alias analysis can hoist
// ds_read st[3L+1] above the ds_writes (no per-lane address overlap), while
// the data flow is CROSS-LANE -> stale logits -> 2.3e-4 kappa error.
// Fix: __threadfence_block() (IR-level fence acq_rel workgroup) between the
// staged writes and the transposing reads. Compiler cannot reorder LDS ops
// across an atomic fence; emits s_waitcnt lgkmcnt(0) so writes are complete.
// ~4 fences per wave per launch -> negligible; hidden by 8 waves/SIMD TLP.
// Structure otherwise = R3:
//   - 512 blocks x 1024 thr = 32 waves/CU (full occupancy) for latency hiding
//   - wave-private LDS bounce: 3 stride-16 coalesced global_load_dwordx4
//     (16 lines/instr vs direct stride-48's 48 lines/instr = 3x TA request
//     inflation) -> linear ds_write_b128 -> stride-48 ds_read_b128.
//     Both LDS phases are bank-PERFECT (12L mod 32 and 4L mod 32 both cover
//     all 32 banks every 8 lanes; 8 phases = minimum for 64x16B).
//   - race-free two-kernel reduction: per-block plain coalesced 144 B store
//     (no global atomics, no device fences -- R2 showed 2048 same-address
//     device atomics + per-block __threadfence cost ~95 us).

#define NC 6
#define NBINS 36
#define BLOCK 1024
#define NWAVES (BLOCK / 64)      // 16 waves per block
#define GRID 512                 // 2 blocks/CU -> full 32 waves/CU
#define CHUNK 64                 // pairs per wave-iteration (192 float4 = 3 KB)
#define SEGS 16
#define FIN_THREADS (NBINS * SEGS)  // 576 = 9 waves

__global__ __launch_bounds__(BLOCK, 8) void kappa_count(
    const float4* __restrict__ yp4, const int2* __restrict__ yt2,
    const float* __restrict__ yp, const int* __restrict__ yt,
    unsigned int* __restrict__ gconf, int npairs, int N) {
    __shared__ float4 stage[NWAVES][3 * CHUNK];   // 48 KB, wave-private rows
    __shared__ unsigned int sconf[NWAVES][NBINS]; // per-wave histograms
    const int tid = threadIdx.x;
    const int w = tid >> 6;
    const int L = tid & 63;
    if (tid < NWAVES * NBINS) ((unsigned int*)sconf)[tid] = 0u;
    __syncthreads();

    unsigned int* my = sconf[w];
    float4* st = stage[w];

    const int nchunks = npairs / CHUNK;
    const int gwaves = GRID * NWAVES;             // 8192 waves in grid
    for (int c = blockIdx.x * NWAVES + w; c < nchunks; c += gwaves) {
        // coalesced: 3 x (64 lanes x 16 B contiguous) + int2 (contiguous 8 B)
        const float4 g0 = yp4[c * 3 * CHUNK + L];
        const float4 g1 = yp4[c * 3 * CHUNK + 64 + L];
        const float4 g2 = yp4[c * 3 * CHUNK + 128 + L];
        const int2 t = yt2[c * CHUNK + L];
        st[L] = g0;
        st[64 + L] = g1;
        st[128 + L] = g2;
        // Cross-lane exchange through LDS: fence is REQUIRED (R3 post-mortem).
        // Orders LDS writes before the reads at IR level + waits lgkmcnt(0).
        __threadfence_block();
        const float4 a = st[3 * L];
        const float4 b = st[3 * L + 1];
        const float4 d = st[3 * L + 2];

        // row 0: a.x a.y a.z a.w b.x b.y (strict > keeps first max = jnp.argmax)
        float m = a.x; int p = 0;
        if (a.y > m) { m = a.y; p = 1; }
        if (a.z > m) { m = a.z; p = 2; }
        if (a.w > m) { m = a.w; p = 3; }
        if (b.x > m) { m = b.x; p = 4; }
        if (b.y > m) { m = b.y; p = 5; }
        atomicAdd(&my[t.x * NC + p], 1u);

        // row 1: b.z b.w d.x d.y d.z d.w
        m = b.z; p = 0;
        if (b.w > m) { m = b.w; p = 1; }
        if (d.x > m) { m = d.x; p = 2; }
        if (d.y > m) { m = d.y; p = 3; }
        if (d.z > m) { m = d.z; p = 4; }
        if (d.w > m) { m = d.w; p = 5; }
        atomicAdd(&my[t.y * NC + p], 1u);
    }

    // leftover pairs (npairs % 64; zero for N=4e6) — direct loads, block 0
    const int rem0 = nchunks * CHUNK;
    if (blockIdx.x == 0 && tid < npairs - rem0) {
        const int i = rem0 + tid;
        const float4 a = yp4[3 * i];
        const float4 b = yp4[3 * i + 1];
        const float4 d = yp4[3 * i + 2];
        const int2 t = yt2[i];
        float m = a.x; int p = 0;
        if (a.y > m) { m = a.y; p = 1; }
        if (a.z > m) { m = a.z; p = 2; }
        if (a.w > m) { m = a.w; p = 3; }
        if (b.x > m) { m = b.x; p = 4; }
        if (b.y > m) { m = b.y; p = 5; }
        atomicAdd(&my[t.x * NC + p], 1u);
        m = b.z; p = 0;
        if (b.w > m) { m = b.w; p = 1; }
        if (d.x > m) { m = d.x; p = 2; }
        if (d.y > m) { m = d.y; p = 3; }
        if (d.z > m) { m = d.z; p = 4; }
        if (d.w > m) { m = d.w; p = 5; }
        atomicAdd(&my[t.y * NC + p], 1u);
    }

    // odd-N tail row (N=4e6 is even; kept for generality)
    if ((N & 1) && blockIdx.x == 0 && tid == 0) {
        const int r = N - 1;
        float m = yp[r * NC]; int p = 0;
        #pragma unroll
        for (int j = 1; j < NC; ++j) {
            const float v = yp[r * NC + j];
            if (v > m) { m = v; p = j; }
        }
        atomicAdd(&my[yt[r] * NC + p], 1u);
    }

    __syncthreads();
    // Race-free per-block writedown: merge 16 wave histograms, one coalesced
    // 144 B store per block. No global atomics, no fences, no prior memset.
    if (tid < NBINS) {
        unsigned int s = 0;
        #pragma unroll
        for (int k = 0; k < NWAVES; ++k) s += sconf[k][tid];
        gconf[blockIdx.x * NBINS + tid] = s;
    }
}

__global__ void kappa_final_kernel(const unsigned int* __restrict__ gconf,
                                   float* __restrict__ out, long long N) {
    // Stage 2a: 576 threads, each sums 32 of the 512 partials for one bin.
    __shared__ unsigned int part[SEGS][NBINS];
    __shared__ unsigned int conf_s[NBINS];
    const int tid = threadIdx.x;
    if (tid < FIN_THREADS) {
        const int bin = tid % NBINS;
        const int seg = tid / NBINS;
        unsigned int s = 0;
        const int b0 = seg * (GRID / SEGS);
        #pragma unroll 8
        for (int b = b0; b < b0 + GRID / SEGS; ++b) s += gconf[b * NBINS + bin];
        part[seg][bin] = s;
    }
    __syncthreads();
    if (tid < NBINS) {
        unsigned int tot = 0;
        #pragma unroll
        for (int s2 = 0; s2 < SEGS; ++s2) tot += part[s2][tid];
        conf_s[tid] = tot;   // per-bin total <= N=4e6, exact in u32
    }
    __syncthreads();
    if (tid == 0) {
        long long conf[NBINS], ht[NC], hp[NC];
        #pragma unroll
        for (int i = 0; i < NC; ++i) { ht[i] = 0; hp[i] = 0; }
        #pragma unroll
        for (int k = 0; k < NBINS; ++k) conf[k] = (long long)conf_s[k];

        long long num = 0;
        #pragma unroll
        for (int i = 0; i < NC; ++i)
            #pragma unroll
            for (int j = 0; j < NC; ++j) {
                const long long w = (long long)(i - j) * (i - j);
                num += w * conf[i * NC + j];
                ht[i] += conf[i * NC + j];
                hp[j] += conf[i * NC + j];
            }
        long long den = 0;
        #pragma unroll
        for (int i = 0; i < NC; ++i)
            #pragma unroll
            for (int j = 0; j < NC; ++j)
                den += (long long)(i - j) * (i - j) * ht[i] * hp[j];

        out[0] = (float)(1.0 - ((double)num * (double)N) / (double)den);
    }
}

extern "C" void kernel_launch(void* const* d_in, const int* in_sizes, int n_in,
                              void* d_out, int out_size, void* d_ws, size_t ws_size,
                              hipStream_t stream) {
    const float* yp = (const float*)d_in[0];
    const int* yt = (const int*)d_in[1];   // int32 on device (verified: absmax=0)
    const int N = in_sizes[1];
    unsigned int* gconf = (unsigned int*)d_ws;  // GRID*NBINS uints = 72 KB

    const int npairs = N / 2;
    kappa_count<<<GRID, BLOCK, 0, stream>>>(
        (const float4*)yp, (const int2*)yt, yp, yt, gconf, npairs, N);
    kappa_final_kernel<<<1, FIN_THREADS, 0, stream>>>(gconf, (float*)d_out,
                                                      (long long)N);
}